// Round 3
// baseline (314.846 us; speedup 1.0000x reference)
//
#include <hip/hip_runtime.h>
#include <hip/hip_fp16.h>
#include <math.h>

// Problem constants
#define NB 392      // n = b*oh*ow = 2*14*14
#define NI 288      // K*K*B = 9*32
#define NC 32       // C
#define NQ 16       // PSIZE
#define CQ 512      // NC*NQ
#define CH 544      // B*(PSIZE+1)
#define EPSV 1e-6f
#define NPAD 400    // n padded to 25 MFMA row-tiles

// element counts (halves for fp16 arrays)
#define P16E (NI*NPAD*32)     // p16[i][n][32k]  fp16, k>=16 zero-pad
#define W16E (NI*CQ*32)       // w16[i][cq][32k] fp16, k>=16 zero-pad
#define AFACE (NB*NI)         // afac floats

// ws float offsets
#define OFF_AFAC 0
#define OFF_P16  (AFACE)
#define OFF_W16  (OFF_P16 + P16E/2)
#define OFF_VOT  (OFF_W16 + W16E/2)

// out layout (floats)
#define OFF_AOUT 200704       // NB*CQ
#define OFF_CAT  213248       // OFF_AOUT + NB*NC

typedef _Float16 v8h __attribute__((ext_vector_type(8)));
typedef float v4f __attribute__((ext_vector_type(4)));

// ---------------------------------------------------------------------------
// Gather from x via the unfold channel-major reinterpret.
// j flat in [0, 544*16): c_idx = j/9, ki = (j%9)/3, kj = j%3
__device__ __forceinline__ float gather_x(const float* __restrict__ x, int n, int j) {
    int c_idx = j / 9;
    int rem = j - c_idx * 9;
    int ki = rem / 3;
    int kj = rem - ki * 3;
    int b_ = n / 196;
    int rest = n - b_ * 196;
    int yy = rest / 14;
    int xx = rest - yy * 14;
    int iy = yy + ki - 1;
    int ix = xx + kj - 1;
    float v = 0.f;
    if ((unsigned)iy < 14u && (unsigned)ix < 14u)
        v = x[((b_ * 14 + iy) * 14 + ix) * CH + c_idx];
    return v;
}

// One elementwise prep kernel: p16 (fp16, padded), w16 (fp16 transposed,
// padded), afac (fp32).
__global__ __launch_bounds__(256) void prep_k(const float* __restrict__ x,
                                              const float* __restrict__ wts,
                                              ushort* __restrict__ p16,
                                              ushort* __restrict__ w16,
                                              float* __restrict__ afac) {
    int tid = blockIdx.x * 256 + threadIdx.x;
    if (tid < P16E) {
        int k = tid & 31;
        int i = tid / (NPAD * 32);
        int n = (tid >> 5) - i * NPAD;
        float v = 0.f;
        if (n < NB && k < 16) {
            int j = (i >> 5) * CH + (i & 31) * 16 + k;
            v = gather_x(x, n, j);
        }
        __half h = __float2half(v);
        p16[tid] = __half_as_ushort(h);
    } else if (tid < P16E + W16E) {
        int t2 = tid - P16E;
        int k = t2 & 31;
        int cq = (t2 >> 5) & 511;
        int i = t2 >> 14;
        float v = 0.f;
        if (k < 16)
            v = wts[i * 8192 + (cq >> 4) * 256 + k * 16 + (cq & 15)];
        __half h = __float2half(v);
        w16[t2] = __half_as_ushort(h);
    } else if (tid < P16E + W16E + AFACE) {
        int t3 = tid - P16E - W16E;
        int i = t3 % NI;
        int n = t3 / NI;
        int j = (i >> 5) * CH + 512 + (i & 31);
        float v = gather_x(x, n, j);
        float a = fminf(fmaxf(v, 1e-4f), 1.0f);
        afac[t3] = a / (a + EPSV);
    }
}

// ---------------------------------------------------------------------------
// votes via MFMA: per block (mt, i): C[16n x 512cq] = A[16n x 32k] @ B[32k x 512cq]
// (K zero-padded 16->32). 1 wave/block. C-frag staged through a 512B LDS tile
// for coalesced fp16 global stores.  votes layout: [n][i][cq] fp16.
__global__ __launch_bounds__(64) void votes_k(const ushort* __restrict__ p16,
                                              const ushort* __restrict__ w16,
                                              ushort* __restrict__ votes) {
    __shared__ ushort tile[2][256];
    int mt = blockIdx.x;          // 0..24
    int i = blockIdx.y;           // 0..287
    int l = threadIdx.x;
    int col = l & 15;
    int quad = l >> 4;

    // A-frag: A[m = mt*16+col][k = quad*8 + j]
    const v8h* ap = (const v8h*)(p16 + ((size_t)(i * NPAD + mt * 16 + col) << 5) + (quad << 3));
    v8h av = *ap;

    int srow = l >> 2;            // store: row within tile
    int scol4 = (l & 3) * 4;      // 4 halves
    int n_out = mt * 16 + srow;
    bool ok = n_out < NB;

    for (int ct = 0; ct < 32; ++ct) {
        // B-frag: B[k = quad*8+j][cq = ct*16+col]  (w16 layout [i][cq][32k])
        const v8h* bp = (const v8h*)(w16 + ((size_t)(i * CQ + ct * 16 + col) << 5) + (quad << 3));
        v8h bv = *bp;
        v4f acc = {0.f, 0.f, 0.f, 0.f};
        acc = __builtin_amdgcn_mfma_f32_16x16x32_f16(av, bv, acc, 0, 0, 0);
        // stage: C rows quad*4+r, col -> LDS [row][col] fp16
        ushort* tl = tile[ct & 1];
#pragma unroll
        for (int r = 0; r < 4; ++r) {
            __half h = __float2half(acc[r]);
            tl[(quad * 4 + r) * 16 + col] = __half_as_ushort(h);
        }
        // read back coalesced: lane -> (row = l>>2, 4 halves at (l&3)*4)
        uint2 d = *(const uint2*)&tl[srow * 16 + scol4];
        if (ok)
            *(uint2*)(votes + ((size_t)n_out * NI + i) * CQ + ct * 16 + scol4) = d;
    }
}

// ---------------------------------------------------------------------------
// Fused dynamic routing: block = n, 512 threads (8 waves).
// Lane: c = l&31, g = l>>5.  Wave wv, step s handles i = (s*8+wv)*2+g.
// Agreement dot is fully in-lane (16 q's in registers); b_ij in registers;
// softmax over c = 1 exp + 5 shfl_xor (no max-sub: |b| <= ~0.2).
__global__ __launch_bounds__(512) void routing_k(const ushort* __restrict__ votes,
                                                 const float* __restrict__ afac,
                                                 float* __restrict__ out) {
    __shared__ float afs[NI];
    __shared__ float sred[16 * CQ];   // 32 KB: 16 partial groups
    __shared__ float vj[CQ];
    __shared__ float aout_s[NC];

    int n = blockIdx.x;
    int t = threadIdx.x;
    int wv = t >> 6;
    int l = t & 63;
    int c = l & 31;
    int g = l >> 5;

    for (int idx = t; idx < NI; idx += 512) afs[idx] = afac[n * NI + idx];
    __syncthreads();

    const ushort* vb = votes + (size_t)n * NI * CQ;
    float breg[18];
#pragma unroll
    for (int s = 0; s < 18; ++s) breg[s] = 0.f;
    float vjr[16];
    float sreg[16];

    for (int iter = 0; iter < 3; ++iter) {
#pragma unroll
        for (int q = 0; q < 16; ++q) sreg[q] = 0.f;

        // depth-2 prefetch: row for (s) and (s+1)
        const uint4* r0 = (const uint4*)(vb + ((size_t)((0 * 8 + wv) * 2 + g) << 9) + (c << 4));
        uint4 a0 = r0[0], a1 = r0[1];
        const uint4* r1 = (const uint4*)(vb + ((size_t)((1 * 8 + wv) * 2 + g) << 9) + (c << 4));
        uint4 b0 = r1[0], b1 = r1[1];

#pragma unroll
        for (int s = 0; s < 18; ++s) {
            int i = ((s << 3) + wv) * 2 + g;
            uint4 c0 = a0, c1 = a1;
            a0 = b0; a1 = b1;
            if (s + 2 < 18) {
                const uint4* rn = (const uint4*)(vb + ((size_t)((((s + 2) << 3) + wv) * 2 + g) << 9) + (c << 4));
                b0 = rn[0]; b1 = rn[1];
            }
            float vt[16];
            {
                float2 f;
                f = __half22float2(*(const __half2*)&c0.x); vt[0] = f.x;  vt[1] = f.y;
                f = __half22float2(*(const __half2*)&c0.y); vt[2] = f.x;  vt[3] = f.y;
                f = __half22float2(*(const __half2*)&c0.z); vt[4] = f.x;  vt[5] = f.y;
                f = __half22float2(*(const __half2*)&c0.w); vt[6] = f.x;  vt[7] = f.y;
                f = __half22float2(*(const __half2*)&c1.x); vt[8] = f.x;  vt[9] = f.y;
                f = __half22float2(*(const __half2*)&c1.y); vt[10] = f.x; vt[11] = f.y;
                f = __half22float2(*(const __half2*)&c1.z); vt[12] = f.x; vt[13] = f.y;
                f = __half22float2(*(const __half2*)&c1.w); vt[14] = f.x; vt[15] = f.y;
            }
            float cij;
            if (iter == 0) {
                cij = afs[i] * (1.0f / 32.0f);
            } else {
                float ah = 0.f;
#pragma unroll
                for (int q = 0; q < 16; ++q) ah += vt[q] * vjr[q];
                float bnew = breg[s] + ah;
                breg[s] = bnew;
                float e = __expf(bnew);   // |b| <= ~0.2: no max-sub needed
                float ssum = e;
                ssum += __shfl_xor(ssum, 1);
                ssum += __shfl_xor(ssum, 2);
                ssum += __shfl_xor(ssum, 4);
                ssum += __shfl_xor(ssum, 8);
                ssum += __shfl_xor(ssum, 16);
                cij = e * __builtin_amdgcn_rcpf(ssum) * afs[i];
            }
#pragma unroll
            for (int q = 0; q < 16; ++q) sreg[q] += cij * vt[q];
        }

        // write 16 partial groups (wave, g) x [c][q]
        {
            float* sw = &sred[((wv << 1) + g) * CQ + (c << 4)];
#pragma unroll
            for (int q4 = 0; q4 < 4; ++q4)
                *(float4*)(sw + q4 * 4) = make_float4(sreg[q4 * 4], sreg[q4 * 4 + 1],
                                                      sreg[q4 * 4 + 2], sreg[q4 * 4 + 3]);
        }
        __syncthreads();
        {
            float ssum = 0.f;
#pragma unroll
            for (int k = 0; k < 16; ++k) ssum += sred[k * CQ + t];
            sred[t] = ssum;   // per-thread column: safe
        }
        __syncthreads();

        // squash (threads 0..31, one c each)
        if (t < NC) {
            float s2 = 0.f;
#pragma unroll
            for (int q = 0; q < 16; ++q) {
                float s = sred[t * 16 + q];
                s2 += s * s;
            }
            float f = (s2 / (1.f + s2)) / sqrtf(s2 + EPSV);
            float vn2 = 0.f;
#pragma unroll
            for (int q = 0; q < 16; ++q) {
                float v = f * sred[t * 16 + q];
                vj[t * 16 + q] = v;
                vn2 += v * v;
            }
            if (iter == 2) {
                float ao = sqrtf(vn2 + EPSV);
                ao = fminf(fmaxf(ao, 1e-4f), 1.f - 1e-4f);
                aout_s[t] = ao;
            }
        }
        __syncthreads();
        if (iter < 2) {
            const float4* vp4 = (const float4*)(&vj[c << 4]);
#pragma unroll
            for (int q4 = 0; q4 < 4; ++q4) {
                float4 f = vp4[q4];
                vjr[q4 * 4] = f.x; vjr[q4 * 4 + 1] = f.y;
                vjr[q4 * 4 + 2] = f.z; vjr[q4 * 4 + 3] = f.w;
            }
        }
    }

    // outputs: p_out, a_out, concat(out)
    {
        float v = vj[t];   // 512 threads == CQ
        out[(size_t)n * CQ + t] = v;
        out[OFF_CAT + (size_t)n * 544 + t] = v;
    }
    if (t < NC) {
        float ao = aout_s[t];
        out[OFF_AOUT + n * 32 + t] = ao;
        out[OFF_CAT + (size_t)n * 544 + 512 + t] = ao;
    }
}

// ---------------------------------------------------------------------------
extern "C" void kernel_launch(void* const* d_in, const int* in_sizes, int n_in,
                              void* d_out, int out_size, void* d_ws, size_t ws_size,
                              hipStream_t stream) {
    const float* x = (const float*)d_in[0];
    const float* wts = (const float*)d_in[1];
    float* out = (float*)d_out;
    float* ws = (float*)d_ws;

    float* afac = ws + OFF_AFAC;
    ushort* p16 = (ushort*)(ws + OFF_P16);
    ushort* w16 = (ushort*)(ws + OFF_W16);
    ushort* votes = (ushort*)(ws + OFF_VOT);

    int prep_tot = P16E + W16E + AFACE;
    hipLaunchKernelGGL(prep_k, dim3((prep_tot + 255) / 256), dim3(256), 0, stream,
                       x, wts, p16, w16, afac);
    hipLaunchKernelGGL(votes_k, dim3(25, NI), dim3(64), 0, stream,
                       p16, w16, votes);
    hipLaunchKernelGGL(routing_k, dim3(NB), dim3(512), 0, stream,
                       votes, afac, out);
}

// Round 4
// 167.833 us; speedup vs baseline: 1.8759x; 1.8759x over previous
//
#include <hip/hip_runtime.h>
#include <hip/hip_fp16.h>
#include <math.h>

// Problem constants
#define NB 392      // n = b*oh*ow = 2*14*14
#define NI 288      // K*K*B = 9*32
#define NC 32       // C
#define NQ 16       // PSIZE
#define CQ 512      // NC*NQ
#define CH 544      // B*(PSIZE+1)
#define EPSV 1e-6f
#define NPAD 400    // n padded to 25 MFMA row-tiles

// element counts (halves for fp16 arrays)
#define P16E (NI*NPAD*32)     // p16[i][n][32k]  fp16, k>=16 zero-pad
#define W16E (NI*CQ*32)       // w16[i][cq][32k] fp16, k>=16 zero-pad
#define AFACE (NB*NI)         // afac floats

// ws float offsets
#define OFF_AFAC 0
#define OFF_P16  (AFACE)
#define OFF_W16  (OFF_P16 + P16E/2)
#define OFF_VOT  (OFF_W16 + W16E/2)

// out layout (floats)
#define OFF_AOUT 200704       // NB*CQ
#define OFF_CAT  213248       // OFF_AOUT + NB*NC

typedef _Float16 v8h __attribute__((ext_vector_type(8)));
typedef float v4f __attribute__((ext_vector_type(4)));

// ---------------------------------------------------------------------------
// Gather from x via the unfold channel-major reinterpret.
// j flat in [0, 544*16): c_idx = j/9, ki = (j%9)/3, kj = j%3
__device__ __forceinline__ float gather_x(const float* __restrict__ x, int n, int j) {
    int c_idx = j / 9;
    int rem = j - c_idx * 9;
    int ki = rem / 3;
    int kj = rem - ki * 3;
    int b_ = n / 196;
    int rest = n - b_ * 196;
    int yy = rest / 14;
    int xx = rest - yy * 14;
    int iy = yy + ki - 1;
    int ix = xx + kj - 1;
    float v = 0.f;
    if ((unsigned)iy < 14u && (unsigned)ix < 14u)
        v = x[((b_ * 14 + iy) * 14 + ix) * CH + c_idx];
    return v;
}

// One elementwise prep kernel: p16 (fp16, padded), w16 (fp16 transposed,
// padded), afac (fp32).
__global__ __launch_bounds__(256) void prep_k(const float* __restrict__ x,
                                              const float* __restrict__ wts,
                                              ushort* __restrict__ p16,
                                              ushort* __restrict__ w16,
                                              float* __restrict__ afac) {
    int tid = blockIdx.x * 256 + threadIdx.x;
    if (tid < P16E) {
        int k = tid & 31;
        int i = tid / (NPAD * 32);
        int n = (tid >> 5) - i * NPAD;
        float v = 0.f;
        if (n < NB && k < 16) {
            int j = (i >> 5) * CH + (i & 31) * 16 + k;
            v = gather_x(x, n, j);
        }
        __half h = __float2half(v);
        p16[tid] = __half_as_ushort(h);
    } else if (tid < P16E + W16E) {
        int t2 = tid - P16E;
        int k = t2 & 31;
        int cq = (t2 >> 5) & 511;
        int i = t2 >> 14;
        float v = 0.f;
        if (k < 16)
            v = wts[i * 8192 + (cq >> 4) * 256 + k * 16 + (cq & 15)];
        __half h = __float2half(v);
        w16[t2] = __half_as_ushort(h);
    } else if (tid < P16E + W16E + AFACE) {
        int t3 = tid - P16E - W16E;
        int i = t3 % NI;
        int n = t3 / NI;
        int j = (i >> 5) * CH + 512 + (i & 31);
        float v = gather_x(x, n, j);
        float a = fminf(fmaxf(v, 1e-4f), 1.0f);
        afac[t3] = a / (a + EPSV);
    }
}

// ---------------------------------------------------------------------------
// votes via MFMA: per block (mt, i): C[16n x 512cq] = A[16n x 32k] @ B[32k x 512cq]
// (K zero-padded 16->32). 1 wave/block. C-frag staged through a 512B LDS tile
// for coalesced fp16 global stores.  votes layout: [n][i][cq] fp16.
__global__ __launch_bounds__(64) void votes_k(const ushort* __restrict__ p16,
                                              const ushort* __restrict__ w16,
                                              ushort* __restrict__ votes) {
    __shared__ ushort tile[2][256];
    int mt = blockIdx.x;          // 0..24
    int i = blockIdx.y;           // 0..287
    int l = threadIdx.x;
    int col = l & 15;
    int quad = l >> 4;

    // A-frag: A[m = mt*16+col][k = quad*8 + j]
    const v8h* ap = (const v8h*)(p16 + ((size_t)(i * NPAD + mt * 16 + col) << 5) + (quad << 3));
    v8h av = *ap;

    int srow = l >> 2;            // store: row within tile
    int scol4 = (l & 3) * 4;      // 4 halves
    int n_out = mt * 16 + srow;
    bool ok = n_out < NB;

    for (int ct = 0; ct < 32; ++ct) {
        // B-frag: B[k = quad*8+j][cq = ct*16+col]  (w16 layout [i][cq][32k])
        const v8h* bp = (const v8h*)(w16 + ((size_t)(i * CQ + ct * 16 + col) << 5) + (quad << 3));
        v8h bv = *bp;
        v4f acc = {0.f, 0.f, 0.f, 0.f};
        acc = __builtin_amdgcn_mfma_f32_16x16x32_f16(av, bv, acc, 0, 0, 0);
        // stage: C rows quad*4+r, col -> LDS [row][col] fp16
        ushort* tl = tile[ct & 1];
#pragma unroll
        for (int r = 0; r < 4; ++r) {
            __half h = __float2half(acc[r]);
            tl[(quad * 4 + r) * 16 + col] = __half_as_ushort(h);
        }
        // read back coalesced: lane -> (row = l>>2, 4 halves at (l&3)*4)
        uint2 d = *(const uint2*)&tl[srow * 16 + scol4];
        if (ok)
            *(uint2*)(votes + ((size_t)n_out * NI + i) * CQ + ct * 16 + scol4) = d;
    }
}

// ---------------------------------------------------------------------------
// Fused dynamic routing: block = n, 512 threads (8 waves).
// Lane: c = l&31, g = l>>5.  Wave wv, step s handles i = (s*8+wv)*2+g.
// Agreement dot fully in-lane. KEY: b_ij is linear in history
// (b_t = <v_ic, sum_{tau<t} vj_tau>), so no per-i logit storage is needed —
// only the cumulative vj (16 regs). This kills the round-3 register spill
// (WRITE_SIZE 88 MB of scratch traffic). unroll_count(2) caps load hoisting.
__global__ __launch_bounds__(512) void routing_k(const ushort* __restrict__ votes,
                                                 const float* __restrict__ afac,
                                                 float* __restrict__ out) {
    __shared__ float afs[NI];
    __shared__ float sred[8 * CQ];    // 16 KB: 8 per-wave partial groups
    __shared__ float vj[CQ];
    __shared__ float aout_s[NC];

    int n = blockIdx.x;
    int t = threadIdx.x;
    int wv = t >> 6;
    int l = t & 63;
    int c = l & 31;
    int g = l >> 5;

    for (int idx = t; idx < NI; idx += 512) afs[idx] = afac[n * NI + idx];
    __syncthreads();

    const ushort* vb = votes + (size_t)n * NI * CQ;
    float vjr[16];    // cumulative sum of vj over past iters
    float sreg[16];

    for (int iter = 0; iter < 3; ++iter) {
#pragma unroll
        for (int q = 0; q < 16; ++q) sreg[q] = 0.f;

        // depth-2 prefetch: rows for s and s+1
        const uint4* r0 = (const uint4*)(vb + ((size_t)((0 * 8 + wv) * 2 + g) << 9) + (c << 4));
        uint4 a0 = r0[0], a1 = r0[1];
        const uint4* r1 = (const uint4*)(vb + ((size_t)((1 * 8 + wv) * 2 + g) << 9) + (c << 4));
        uint4 b0 = r1[0], b1 = r1[1];

#pragma clang loop unroll_count(2)
        for (int s = 0; s < 18; ++s) {
            int i = ((s << 3) + wv) * 2 + g;
            uint4 c0 = a0, c1 = a1;
            a0 = b0; a1 = b1;
            if (s + 2 < 18) {
                const uint4* rn = (const uint4*)(vb + ((size_t)((((s + 2) << 3) + wv) * 2 + g) << 9) + (c << 4));
                b0 = rn[0]; b1 = rn[1];
            }
            float vt[16];
            {
                float2 f;
                f = __half22float2(*(const __half2*)&c0.x); vt[0] = f.x;  vt[1] = f.y;
                f = __half22float2(*(const __half2*)&c0.y); vt[2] = f.x;  vt[3] = f.y;
                f = __half22float2(*(const __half2*)&c0.z); vt[4] = f.x;  vt[5] = f.y;
                f = __half22float2(*(const __half2*)&c0.w); vt[6] = f.x;  vt[7] = f.y;
                f = __half22float2(*(const __half2*)&c1.x); vt[8] = f.x;  vt[9] = f.y;
                f = __half22float2(*(const __half2*)&c1.y); vt[10] = f.x; vt[11] = f.y;
                f = __half22float2(*(const __half2*)&c1.z); vt[12] = f.x; vt[13] = f.y;
                f = __half22float2(*(const __half2*)&c1.w); vt[14] = f.x; vt[15] = f.y;
            }
            float cij;
            if (iter == 0) {
                cij = afs[i] * (1.0f / 32.0f);
            } else {
                float ah = 0.f;
#pragma unroll
                for (int q = 0; q < 16; ++q) ah += vt[q] * vjr[q];
                float e = __expf(ah);   // |b| <= ~0.7: no max-sub needed
                float ssum = e;
                ssum += __shfl_xor(ssum, 1);
                ssum += __shfl_xor(ssum, 2);
                ssum += __shfl_xor(ssum, 4);
                ssum += __shfl_xor(ssum, 8);
                ssum += __shfl_xor(ssum, 16);
                cij = e * __builtin_amdgcn_rcpf(ssum) * afs[i];
            }
#pragma unroll
            for (int q = 0; q < 16; ++q) sreg[q] += cij * vt[q];
        }

        // fold the two g-halves in-wave, then write 8 partial groups [c][q]
#pragma unroll
        for (int q = 0; q < 16; ++q) sreg[q] += __shfl_xor(sreg[q], 32);
        if (g == 0) {
            float* sw = &sred[wv * CQ + (c << 4)];
#pragma unroll
            for (int q4 = 0; q4 < 4; ++q4)
                *(float4*)(sw + q4 * 4) = make_float4(sreg[q4 * 4], sreg[q4 * 4 + 1],
                                                      sreg[q4 * 4 + 2], sreg[q4 * 4 + 3]);
        }
        __syncthreads();
        {
            float ssum = 0.f;
#pragma unroll
            for (int k = 0; k < 8; ++k) ssum += sred[k * CQ + t];
            sred[t] = ssum;   // per-thread column: safe
        }
        __syncthreads();

        // squash (threads 0..31, one c each)
        if (t < NC) {
            float s2 = 0.f;
#pragma unroll
            for (int q = 0; q < 16; ++q) {
                float s = sred[t * 16 + q];
                s2 += s * s;
            }
            float f = (s2 / (1.f + s2)) / sqrtf(s2 + EPSV);
            float vn2 = 0.f;
#pragma unroll
            for (int q = 0; q < 16; ++q) {
                float v = f * sred[t * 16 + q];
                vj[t * 16 + q] = v;
                vn2 += v * v;
            }
            if (iter == 2) {
                float ao = sqrtf(vn2 + EPSV);
                ao = fminf(fmaxf(ao, 1e-4f), 1.f - 1e-4f);
                aout_s[t] = ao;
            }
        }
        __syncthreads();
        if (iter < 2) {
            const float4* vp4 = (const float4*)(&vj[c << 4]);
#pragma unroll
            for (int q4 = 0; q4 < 4; ++q4) {
                float4 f = vp4[q4];
                if (iter == 0) {
                    vjr[q4 * 4] = f.x; vjr[q4 * 4 + 1] = f.y;
                    vjr[q4 * 4 + 2] = f.z; vjr[q4 * 4 + 3] = f.w;
                } else {
                    vjr[q4 * 4] += f.x; vjr[q4 * 4 + 1] += f.y;
                    vjr[q4 * 4 + 2] += f.z; vjr[q4 * 4 + 3] += f.w;
                }
            }
        }
    }

    // outputs: p_out, a_out, concat(out)
    {
        float v = vj[t];   // 512 threads == CQ
        out[(size_t)n * CQ + t] = v;
        out[OFF_CAT + (size_t)n * 544 + t] = v;
    }
    if (t < NC) {
        float ao = aout_s[t];
        out[OFF_AOUT + n * 32 + t] = ao;
        out[OFF_CAT + (size_t)n * 544 + 512 + t] = ao;
    }
}

// ---------------------------------------------------------------------------
extern "C" void kernel_launch(void* const* d_in, const int* in_sizes, int n_in,
                              void* d_out, int out_size, void* d_ws, size_t ws_size,
                              hipStream_t stream) {
    const float* x = (const float*)d_in[0];
    const float* wts = (const float*)d_in[1];
    float* out = (float*)d_out;
    float* ws = (float*)d_ws;

    float* afac = ws + OFF_AFAC;
    ushort* p16 = (ushort*)(ws + OFF_P16);
    ushort* w16 = (ushort*)(ws + OFF_W16);
    ushort* votes = (ushort*)(ws + OFF_VOT);

    int prep_tot = P16E + W16E + AFACE;
    hipLaunchKernelGGL(prep_k, dim3((prep_tot + 255) / 256), dim3(256), 0, stream,
                       x, wts, p16, w16, afac);
    hipLaunchKernelGGL(votes_k, dim3(25, NI), dim3(64), 0, stream,
                       p16, w16, votes);
    hipLaunchKernelGGL(routing_k, dim3(NB), dim3(512), 0, stream,
                       votes, afac, out);
}